// Round 8
// baseline (250.525 us; speedup 1.0000x reference)
//
#include <hip/hip_runtime.h>

// CustomConv2d: 3x3 conv, stride 1, pad 1. B=32, Cin=128, H=W=56, Cout=256.
// fp32 in/out (round-1 NaN proved it); per-wave dtype self-detection keeps
// robustness without a separate serialized detect dispatch.
//
// Implicit GEMM, internally bf16. M=cout(256), N=b*h*w(100352), K=cin*9(1152).
// Round-13: rounds 9 vs 12 isolated the cost cleanly: counted in-flight
// pipelining (r9, 86.5us) beats a per-half vmcnt(0) drain (r12, 109us) by
// 22us; A-removal alone gained nothing through a drain. This round removes
// the structure both pay for: the barrier. NO LDS, NO SYNC in conv_mfma:
//   - A: fragment-ordered wt (576KB, L2-hot, shared by all 784 blocks);
//     each wave's A-operand is a coalesced 1KB load, ping-pong registers
//   - B: loaded DIRECTLY from xp into registers: lane addr =
//     spatial(n)*256B + hi*16B; a wave touches 16 x 64B segments (L1
//     catches the wm-pair reuse). The LDS XOR swizzle disappears with the
//     LDS; reader uses plain hi = lane>>4 chunk mapping.
//   - per half per wave: 8 A + 4 B dwordx4 loads, then 32 MFMA; prefetch
//     h+1 issued before MFMA(h) -> compiler emits exactly the counted
//     vmcnt(12) gate round-10 hand-built, but correct by construction
//   - addressing: uniform per-half deltas fold to SGPR base bumps; per-lane
//     voffsets are loop-invariant -> near-zero VALU in steady state
//   - regs: acc 128 AGPR + afA/afB 64 + bfA/bfB 32 + bases ~14 ~= 240/252
//   - 2 blocks/CU (reg-limited), unsynchronized waves cover each other's
//     HBM-miss stalls; XCD swizzle (784=8x98) keeps xp slice L2-resident

typedef __attribute__((ext_vector_type(8))) short short8;
typedef __attribute__((ext_vector_type(4))) float floatx4;

__device__ static inline float bf2f(unsigned short u) {
    union { unsigned int i; float f; } x; x.i = ((unsigned int)u) << 16; return x.f;
}
__device__ static inline unsigned short f2bf(float f) {
    union { float f; unsigned int i; } x; x.f = f;
    unsigned int r = (x.i + 0x7FFFu + ((x.i >> 16) & 1u)) >> 16;  // RNE
    return (unsigned short)r;
}

// Per-wave dtype sniff: low halves of fp32 words are random mantissa bits
// (~19% plausible bf16 exponents); true bf16 data is ~100% plausible.
// Uniform across the wave via ballot; requires all 64 lanes active.
__device__ static inline bool wave_detect_bf16(const unsigned int* __restrict__ p) {
    const int lane = threadIdx.x & 63;
    int cnt = 0;
#pragma unroll
    for (int r = 0; r < 4; ++r) {
        unsigned int w = p[r * 64 + lane];
        unsigned short lo = (unsigned short)(w & 0xFFFFu);
        int e = (lo >> 7) & 0xFF;
        bool plaus = (lo == 0) || (e >= 96 && e <= 144);
        cnt += (int)__popcll(__ballot(plaus));
    }
    return cnt >= 205;   // >=80% of 256 sampled halves
}

// ------ weight repack -> fragment order [36][2][8][64] 16B chunks ---------
// Chunk (h=off*4+q, wm, i, lane) holds A[co=wm*128+i*16+(lane&15)]
// [ci=q*32+(lane>>4)*8 .. +8) as 8 bf16. conv_mfma lane l then loads its
// MFMA A-fragment at ushort index h*8192 + wm*4096 + i*512 + l*8.
__global__ void wt_repack(const void* __restrict__ wsrc,
                          unsigned short* __restrict__ wt) {
    const bool isbf = wave_detect_bf16((const unsigned int*)wsrc);
    int idx  = blockIdx.x * 256 + threadIdx.x;   // 36864 chunks, grid=144
    int lane = idx & 63;
    int i    = (idx >> 6) & 7;
    int wm   = (idx >> 9) & 1;
    int q    = (idx >> 10) & 3;
    int off  = idx >> 12;                        // 0..8 = dh*3+dw
    int co   = wm * 128 + i * 16 + (lane & 15);
    int ci0  = q * 32 + (lane >> 4) * 8;
    union { unsigned short s[8]; uint4 u; } pk;
#pragma unroll
    for (int e = 0; e < 8; ++e) {
        size_t s = (size_t)(co * 128 + ci0 + e) * 9 + off;
        float v = isbf ? bf2f(((const unsigned short*)wsrc)[s])
                       : ((const float*)wsrc)[s];
        pk.s[e] = f2bf(v);
    }
    *(uint4*)(wt + (size_t)idx * 8) = pk.u;
}

// ------- x NCHW -> padded NHWC bf16 [32][58][58][128], LDS transpose -------
__global__ __launch_bounds__(256) void x_repack(
    const void* __restrict__ xsrc, unsigned short* __restrict__ xp) {
    __shared__ unsigned short tile[56 * 130];   // pad 130: conflict-free
    const int bh  = blockIdx.x;                 // 32*58 blocks
    const int b   = bh / 58, hp = bh - b * 58;  // hp in [0,58)
    const int tid = threadIdx.x;
    unsigned short* row = xp + (size_t)(b * 58 + hp) * 58 * 128;
    if (hp == 0 || hp == 57) {                  // top/bottom pad rows
        uint4 z; z.x = z.y = z.z = z.w = 0u;
        uint4* r = (uint4*)row;
        for (int t = tid; t < 928; t += 256) r[t] = z;
        return;
    }
    const bool isbf = wave_detect_bf16((const unsigned int*)xsrc);
    const int h = hp - 1;
    if (isbf) {
        const unsigned short* xs =
            (const unsigned short*)xsrc + (size_t)b * 128 * 3136 + h * 56;
#pragma unroll
        for (int it = 0; it < 7; ++it) {        // 1792 items = 128ci x 14 w4
            int idx = it * 256 + tid;
            int ci = idx / 14, w4 = idx - ci * 14;
            ushort4 v = *(const ushort4*)(xs + (size_t)ci * 3136 + w4 * 4);
            tile[(w4 * 4 + 0) * 130 + ci] = v.x;
            tile[(w4 * 4 + 1) * 130 + ci] = v.y;
            tile[(w4 * 4 + 2) * 130 + ci] = v.z;
            tile[(w4 * 4 + 3) * 130 + ci] = v.w;
        }
    } else {
        const float* xs = (const float*)xsrc + (size_t)b * 128 * 3136 + h * 56;
#pragma unroll
        for (int it = 0; it < 7; ++it) {
            int idx = it * 256 + tid;
            int ci = idx / 14, w4 = idx - ci * 14;
            float4 v = *(const float4*)(xs + (size_t)ci * 3136 + w4 * 4);
            tile[(w4 * 4 + 0) * 130 + ci] = f2bf(v.x);
            tile[(w4 * 4 + 1) * 130 + ci] = f2bf(v.y);
            tile[(w4 * 4 + 2) * 130 + ci] = f2bf(v.z);
            tile[(w4 * 4 + 3) * 130 + ci] = f2bf(v.w);
        }
    }
    __syncthreads();
#pragma unroll
    for (int it = 0; it < 4; ++it) {
        int k = it * 256 + tid;                 // 928 chunks of 16B
        if (k >= 928) break;
        int wq = k >> 4, cc = k & 15;
        uint4 v;
        if (wq == 0 || wq == 57) { v.x = v.y = v.z = v.w = 0u; }
        else {
            const unsigned short* p = &tile[(wq - 1) * 130 + cc * 8];
            union { unsigned short s[8]; uint4 u; } pk;
#pragma unroll
            for (int j = 0; j < 8; ++j) pk.s[j] = p[j];
            v = pk.u;
        }
        *(uint4*)(row + wq * 128 + cc * 8) = v;
    }
}

// -------- main: 4-wave 128x64-per-wave implicit GEMM, 256x128 tile ---------
// NO LDS, NO BARRIERS. A and B both direct-to-register from global with
// one-half-ahead ping-pong prefetch. Halves h=0..35: h=(dh*3+dw)*4+q.
__global__ __launch_bounds__(256, 2) void conv_mfma(
    const unsigned short* __restrict__ xp,   // [32][58][58][128] bf16
    const unsigned short* __restrict__ wt,   // fragment-order, 589824 B
    const void* __restrict__ bias,           // [256] fp32 or bf16
    void* __restrict__ out,                  // [32][256][56][56] fp32 or bf16
    const void* __restrict__ xorig)          // for dtype sniff only
{
    const int tid   = threadIdx.x;
    const int lane  = tid & 63;
    const int wv    = tid >> 6;        // 0..3
    const int bid   = blockIdx.x;
    const int ntile = (bid & 7) * 98 + (bid >> 3);   // XCD swizzle, 784=8x98

    const bool isbf = wave_detect_bf16((const unsigned int*)xorig);

    const int fr = lane & 15;
    const int hi = lane >> 4;          // k-chunk 0..3 (plain, no LDS swizzle)
    const int wm = wv >> 1;            // 0..1  (M: 128 couts per wave)
    const int wn = wv & 1;             // 0..1  (N: 64 cols per wave)

    // A: per-lane base into fragment-ordered wt (ushort units); +8192/half.
    const unsigned short* aP = wt + (wm * 4096 + lane * 8);

    // B: per-lane fragment bases for j=0..3 (ushort units); per-half delta
    // dB = ((dh*58+dw)*128 + q*32) is wave-uniform.
    const unsigned short* bP[4];
#pragma unroll
    for (int j = 0; j < 4; ++j) {
        const int n = ntile * 128 + wn * 64 + j * 16 + fr;
        const int b = n / 3136, rem = n - b * 3136;
        const int hh = rem / 56, ww = rem - hh * 56;
        bP[j] = xp + (size_t)((b * 58 + hh) * 58 + ww) * 128 + hi * 8;
    }

    floatx4 acc[8][4] = {};
    short8 afA[8], afB[8], bfA[4], bfB[4];

    // ---- prologue: load half 0 (off=0, q=0 -> deltas 0) -------------------
#pragma unroll
    for (int j = 0; j < 4; ++j) bfA[j] = *(const short8*)(bP[j]);
#pragma unroll
    for (int i = 0; i < 8; ++i) afA[i] = *(const short8*)(aP + i * 512);

// Body for half H (H <= 34): issue prefetch of half H+1 into (AL, BL),
// then 32 MFMA on (AU, BU). The compiler's automatic wait before the MFMA
// cluster is vmcnt(12) — exactly the counted gate, by construction.
#define BODY(H, AU, AL, BU, BL)                                            \
  {                                                                        \
    const int hn = (H) + 1, off_ = hn >> 2, qq = hn & 3;                   \
    const int dh_ = off_ / 3, dw_ = off_ - dh_ * 3;                        \
    const int dB = (dh_ * 58 + dw_) * 128 + qq * 32;                       \
    _Pragma("unroll")                                                      \
    for (int j_ = 0; j_ < 4; ++j_)                                         \
        BL[j_] = *(const short8*)(bP[j_] + dB);                            \
    {                                                                      \
        const unsigned short* aN = aP + (size_t)hn * 8192;                 \
        _Pragma("unroll")                                                  \
        for (int i_ = 0; i_ < 8; ++i_)                                     \
            AL[i_] = *(const short8*)(aN + i_ * 512);                      \
    }                                                                      \
    __builtin_amdgcn_s_setprio(1);                                         \
    _Pragma("unroll")                                                      \
    for (int i_ = 0; i_ < 8; ++i_) {                                       \
        _Pragma("unroll")                                                  \
        for (int j_ = 0; j_ < 4; ++j_)                                     \
            acc[i_][j_] = __builtin_amdgcn_mfma_f32_16x16x32_bf16(         \
                AU[i_], BL == bfB ? BU[j_] : BU[j_], acc[i_][j_], 0, 0, 0);\
    }                                                                      \
    __builtin_amdgcn_s_setprio(0);                                         \
  }

    for (int h = 0; h < 34; h += 2) {
        BODY(h,     afA, afB, bfA, bfB);
        BODY(h + 1, afB, afA, bfB, bfA);
    }
    BODY(34, afA, afB, bfA, bfB);     // prefetches half 35 into afB/bfB
    // ---- h = 35: consume afB/bfB, no prefetch ----------------------------
    __builtin_amdgcn_s_setprio(1);
#pragma unroll
    for (int i_ = 0; i_ < 8; ++i_)
#pragma unroll
        for (int j_ = 0; j_ < 4; ++j_)
            acc[i_][j_] = __builtin_amdgcn_mfma_f32_16x16x32_bf16(
                afB[i_], bfB[j_], acc[i_][j_], 0, 0, 0);
    __builtin_amdgcn_s_setprio(0);

    // ---- epilogue: D[row=cout(quad*4+reg)][col=spatial(lane&15)] ----------
    const int q4 = hi << 2;
    int nb[4], ns[4];
#pragma unroll
    for (int j = 0; j < 4; ++j) {
        const int n = ntile * 128 + wn * 64 + j * 16 + fr;
        nb[j] = n / 3136;
        ns[j] = n - nb[j] * 3136;
    }
#pragma unroll
    for (int i = 0; i < 8; ++i) {
        const int co = wm * 128 + i * 16 + q4;
        float bv[4];
        if (isbf) {
            const ushort4 bb = *(const ushort4*)((const unsigned short*)bias + co);
            bv[0] = bf2f(bb.x); bv[1] = bf2f(bb.y);
            bv[2] = bf2f(bb.z); bv[3] = bf2f(bb.w);
        } else {
            const float4 bb = *(const float4*)((const float*)bias + co);
            bv[0] = bb.x; bv[1] = bb.y; bv[2] = bb.z; bv[3] = bb.w;
        }
#pragma unroll
        for (int j = 0; j < 4; ++j) {
#pragma unroll
            for (int r = 0; r < 4; ++r) {
                const float v = acc[i][j][r] + bv[r];
                const size_t o = (size_t)nb[j] * 802816 +
                                 (size_t)(co + r) * 3136 + ns[j];
                if (isbf) ((unsigned short*)out)[o] = f2bf(v);
                else      ((float*)out)[o] = v;
            }
        }
    }
}

// ---------------- fallback: naive direct conv fp32 (if ws too small) -------
__global__ void conv_naive(const float* __restrict__ x,
                           const float* __restrict__ w,
                           const float* __restrict__ bias,
                           float* __restrict__ out) {
    long long i = (long long)blockIdx.x * 256 + threadIdx.x;
    if (i >= 25690112LL) return;
    int wo = (int)(i % 56); long long t = i / 56;
    int ho = (int)(t % 56); t /= 56;
    int co = (int)(t % 256); int b = (int)(t / 256);
    float acc = bias[co];
    for (int ci = 0; ci < 128; ++ci)
        for (int dh = 0; dh < 3; ++dh) {
            int hi = ho + dh - 1; if ((unsigned)hi >= 56u) continue;
            for (int dw = 0; dw < 3; ++dw) {
                int wi = wo + dw - 1; if ((unsigned)wi >= 56u) continue;
                acc += x[((size_t)(b * 128 + ci) * 56 + hi) * 56 + wi] *
                       w[((co * 128 + ci) * 3 + dh) * 3 + dw];
            }
        }
    out[i] = acc;
}

extern "C" void kernel_launch(void* const* d_in, const int* in_sizes, int n_in,
                              void* d_out, int out_size, void* d_ws, size_t ws_size,
                              hipStream_t stream) {
    const void* x    = d_in[0];
    const void* w    = d_in[1];
    const void* bias = d_in[2];
    // d_in[3] = approximate (scalar, does not affect exact math) — unused.

    const size_t xp_bytes = (size_t)32 * 58 * 58 * 128 * 2;   // 27,557,888
    const size_t wt_off   = xp_bytes;
    const size_t wt_bytes = (size_t)9 * 256 * 128 * 2;        // 589,824
    const size_t need     = wt_off + wt_bytes;

    if (ws_size >= need) {
        unsigned short* xp = (unsigned short*)d_ws;
        unsigned short* wt = (unsigned short*)((char*)d_ws + wt_off);
        x_repack<<<32 * 58, 256, 0, stream>>>(x, xp);
        wt_repack<<<144, 256, 0, stream>>>(w, wt);
        conv_mfma<<<dim3(784, 1, 1), 256, 0, stream>>>(xp, wt, bias, d_out, x);
    } else {
        conv_naive<<<(25690112 + 255) / 256, 256, 0, stream>>>(
            (const float*)x, (const float*)w, (const float*)bias, (float*)d_out);
    }
}